// Round 5
// baseline (373.500 us; speedup 1.0000x reference)
//
#include <hip/hip_runtime.h>
#include <hip/hip_bf16.h>

// B=4, NV=50000, NRINGS=3, NDIRS=16, NF=16. All f32 except expmap(int32).
// MFMA: per vertex D[16d x 16f] = A[16d x 144k] * W[144k x 16f], k = dd*9 + q.
// R11 = R6 (known-good 132us/dispatch) + three independent low-risk changes:
//  (1) neighbor gather = ONE guarded global_load_dwordx4 (12B used) instead of
//      3 scalar dwords: 9 -> 3 divergent VMEM insts per staging thread. TA
//      line-request processing was the largest modeled cost (~47us/CU).
//      Guard: only nb==B*NV-1 would read 4B past the buffer -> scalar path.
//  (2) LDS copy-1 offset CP1: 303 -> 295. Fragment-read dword residues:
//      even-f set {9g mod16}, odd-f set shifted by C=(CP1+9)/2 mod 16.
//      CP1=295 -> C=8 -> odd set = exact complement -> all 32 (f,q%2) combos
//      hit distinct banks -> uniform 2-way (free, m136) instead of half-4-way.
//      Same 608-elem stride, same parity/alignment structure, same LDS size.
//  (3) __launch_bounds__(256, 8): LDS 19456B allows 8 blocks/CU; VGPR 36<64.
//  Epilogue = R6 scattered stores (R10 PROVED coalescing-via-LDS loses 12us:
//  stores are not the bottleneck; do not revisit).
//  MFMA operand order mfma(Y,W) is load-bearing: R9 proved the swap breaks
//  (A-operand lane map unverified for generic data on circulant A). Keep.
#define NBATCH 4
#define NV     50000
#define VPB    16          // vertices per block (4 waves x 4 vertices)
#define VST    304         // per-vertex stride = 2*VST elems (19456B total)
#define CP1    295         // copy-1 element offset: odd, ==7 mod 32 (bank fix)

typedef __attribute__((ext_vector_type(8))) short short8;
typedef __attribute__((ext_vector_type(4))) float floatx4;

// ---- pre-kernel: build per-lane W fragments (bf16) into d_ws ----
// layout: lane*40 + kc*8 ushorts (16B per chunk, 80B per lane, 5120B total)
__global__ void build_wfrag(const float* __restrict__ kw,
                            unsigned short* __restrict__ wbuf) {
    const int lane = threadIdx.x;      // 0..63
    const int fcol = lane & 15;
    const int quad = lane >> 4;
    #pragma unroll
    for (int kc = 0; kc < 5; ++kc) {
        unsigned short v[8];
        #pragma unroll
        for (int j = 0; j < 8; ++j) {
            int k = kc * 32 + quad * 8 + j;
            unsigned short b = 0;
            if (k < 144) {
                int dd = k / 9;
                int q  = k - dd * 9;
                int r  = q / 3;
                int c  = q - r * 3;
                __hip_bfloat16 h = __float2bfloat16(kw[((r * 16 + dd) * 3 + c) * 16 + fcol]);
                __builtin_memcpy(&b, &h, 2);
            }
            v[j] = b;
        }
        __builtin_memcpy(wbuf + lane * 40 + kc * 8, v, 16);
    }
}

__global__ __launch_bounds__(256, 8)
void input3d_mfma(const float* __restrict__ bp,     // (B,NV,3)
                  const float* __restrict__ fr,     // (B,NV,3,3)
                  const int2*  __restrict__ em,     // (B,NV,3,16) int pairs
                  const unsigned short* __restrict__ wbuf, // prebuilt W frags
                  const float* __restrict__ bias,   // (16)
                  float*       __restrict__ out)    // (B,NV,16,16)
{
    __shared__ __align__(16) unsigned short yls[VPB * 2 * VST];   // 19456 B

    const int tid  = threadIdx.x;
    const int bv0  = blockIdx.x * VPB;
    const int lane = tid & 63;
    const int wid  = tid >> 6;
    const int fcol = lane & 15;
    const int quad = lane >> 4;

    // ---- load prebuilt W fragments: 5 x dwordx4 ----
    union WU { unsigned short s[8]; short8 v; };
    WU wf[5];
    const unsigned short* wl = wbuf + lane * 40;
    #pragma unroll
    for (int kc = 0; kc < 5; ++kc)
        __builtin_memcpy(&wf[kc].s[0], wl + kc * 8, 16);
    const float bsf = bias[fcol];

    // ---- staging: thread = (v = tid>>4, dir = tid&15) ----
    {
        const int v   = tid >> 4;
        const int dir = tid & 15;
        const int bv  = bv0 + v;
        float F[9];
        __builtin_memcpy(&F[0], fr + (size_t)bv * 9, 16);
        __builtin_memcpy(&F[4], fr + (size_t)bv * 9 + 4, 16);
        F[8] = fr[(size_t)bv * 9 + 8];
        const float c0 = bp[bv * 3 + 0];
        const float c1 = bp[bv * 3 + 1];
        const float c2 = bp[bv * 3 + 2];

        unsigned short val[9];
        #pragma unroll
        for (int r = 0; r < 3; ++r) {
            int2 e  = em[bv * 48 + r * 16 + dir];
            int nb  = e.x * NV + e.y;
            const float* bn = bp + (size_t)nb * 3;
            float g0, g1, g2;
            if (nb < NBATCH * NV - 1) {
                floatx4 g;                       // 16B load, 12B used; 4B-aligned
                __builtin_memcpy(&g, bn, 16);    // emits global_load_dwordx4
                g0 = g[0]; g1 = g[1]; g2 = g[2];
            } else {                             // last vertex: avoid 4B OOB
                g0 = bn[0]; g1 = bn[1]; g2 = bn[2];
            }
            float dx = g0 - c0;
            float dy = g1 - c1;
            float dz = g2 - c2;
            #pragma unroll
            for (int c = 0; c < 3; ++c) {
                float yv = F[c * 3 + 0] * dx + F[c * 3 + 1] * dy + F[c * 3 + 2] * dz;
                __hip_bfloat16 h = __float2bfloat16(yv);
                unsigned short us;
                __builtin_memcpy(&us, &h, 2);
                val[r * 3 + c] = us;
            }
        }

        // packed 9-element group writes (4 x b32 + 1 x u16 per group)
        unsigned short* buf = &yls[v * 2 * VST];
        unsigned int pe[4], po[4];
        #pragma unroll
        for (int i = 0; i < 4; ++i) {
            pe[i] = (unsigned int)val[2 * i]     | ((unsigned int)val[2 * i + 1] << 16);
            po[i] = (unsigned int)val[2 * i + 1] | ((unsigned int)val[2 * i + 2] << 16);
        }
        const int n0 = dir * 9;
        // even-start group: dwords at s, tail u16 at s+8
        auto storeE = [&](int s) {
            unsigned int* p = (unsigned int*)(buf + s);
            p[0] = pe[0]; p[1] = pe[1]; p[2] = pe[2]; p[3] = pe[3];
            buf[s + 8] = val[8];
        };
        // odd-start group: head u16 at s, dwords at s+1
        auto storeO = [&](int s) {
            buf[s] = val[0];
            unsigned int* p = (unsigned int*)(buf + s + 1);
            p[0] = po[0]; p[1] = po[1]; p[2] = po[2]; p[3] = po[3];
        };
        if (dir & 1) {                 // n0 odd
            storeO(n0);
            storeE(CP1 + n0);          // 295+odd = even start
            if (dir < 15) { storeO(n0 + 144); storeE(CP1 + n0 + 144); }
        } else {                       // n0 even
            storeE(n0);
            storeO(CP1 + n0);          // 295+even = odd start
            if (dir < 15) { storeE(n0 + 144); storeO(CP1 + n0 + 144); }
        }
    }
    __syncthreads();

    // ---- per wave: 4 vertices, 5 MFMA each (K=144 exact) ----
    floatx4 acc[4] = {{0.f,0.f,0.f,0.f},{0.f,0.f,0.f,0.f},
                      {0.f,0.f,0.f,0.f},{0.f,0.f,0.f,0.f}};
    const unsigned short* abase[4];
    #pragma unroll
    for (int i = 0; i < 4; ++i) {
        int v = wid * 4 + i;
        abase[i] = &yls[v * 2 * VST + ((fcol & 1) ? CP1 : 0) + 9 * fcol];
    }
    #pragma unroll
    for (int kc = 0; kc < 4; ++kc) {
        const int s = kc * 32 + quad * 8;
        #pragma unroll
        for (int i = 0; i < 4; ++i) {
            const unsigned int* pa = (const unsigned int*)(abase[i] + s);
            union { unsigned int u[4]; short8 s8; } a;
            a.u[0] = pa[0]; a.u[1] = pa[1]; a.u[2] = pa[2]; a.u[3] = pa[3];
            acc[i] = __builtin_amdgcn_mfma_f32_16x16x32_bf16(a.s8, wf[kc].v, acc[i], 0, 0, 0);
        }
    }
    {   // chunk 4: k = 128 + quad*8 + j; valid k<144 only for quads 0,1.
        const int s = 128 + quad * 8;
        #pragma unroll
        for (int i = 0; i < 4; ++i) {
            union { unsigned int u[4]; short8 s8; } a;
            if (quad < 2) {
                const unsigned int* pa = (const unsigned int*)(abase[i] + s);
                a.u[0] = pa[0]; a.u[1] = pa[1]; a.u[2] = pa[2]; a.u[3] = pa[3];
            } else {
                a.u[0] = 0; a.u[1] = 0; a.u[2] = 0; a.u[3] = 0;
            }
            acc[i] = __builtin_amdgcn_mfma_f32_16x16x32_bf16(a.s8, wf[4].v, acc[i], 0, 0, 0);
        }
    }

    // ---- epilogue: R6 scattered stores (R10 proved LDS-transpose loses) ----
    // C layout col=lane&15=f, row=quad*4+reg=d -> direct store.
    #pragma unroll
    for (int i = 0; i < 4; ++i) {
        int vg = bv0 + wid * 4 + i;
        float* ob = out + (size_t)vg * 256;
        #pragma unroll
        for (int rr = 0; rr < 4; ++rr) {
            float o = acc[i][rr] + bsf;
            o = o > 0.f ? o : 0.f;
            ob[(quad * 4 + rr) * 16 + fcol] = o;
        }
    }
}

extern "C" void kernel_launch(void* const* d_in, const int* in_sizes, int n_in,
                              void* d_out, int out_size, void* d_ws, size_t ws_size,
                              hipStream_t stream) {
    const float* bp   = (const float*)d_in[0];
    const float* fr   = (const float*)d_in[1];
    const int2*  em   = (const int2*)d_in[2];
    const float* kw   = (const float*)d_in[3];
    const float* bias = (const float*)d_in[4];
    float* out = (float*)d_out;
    unsigned short* wbuf = (unsigned short*)d_ws;   // 5120 B used

    build_wfrag<<<1, 64, 0, stream>>>(kw, wbuf);

    const int total_bv = NBATCH * NV;          // 200000
    const int grid = total_bv / VPB;           // 12500 blocks
    input3d_mfma<<<grid, 256, 0, stream>>>(bp, fr, em, wbuf, bias, out);
}

// Round 6
// 343.881 us; speedup vs baseline: 1.0861x; 1.0861x over previous
//
#include <hip/hip_runtime.h>
#include <hip/hip_bf16.h>

// B=4, NV=50000, NRINGS=3, NDIRS=16, NF=16. All f32 except expmap(int32).
// MFMA: per vertex D[16d x 16f] = A[16d x 144k] * W[144k x 16f], k = dd*9 + q.
// R12 = R6 logic with ONE structural change: 64-thread (1-wave) blocks.
//   VPB=4, grid=50000. Producer threads (v=tid>>4 in 0..3) and the consumer
//   wave are the SAME wave, so the inter-wave barrier coupling of the 256-
//   thread block (each wave waiting on max-of-256-lane gather latency, then
//   post-barrier LDS/VALU burst) disappears. __syncthreads() RETAINED: for a
//   1-wave workgroup s_barrier is immediate, and it provides the full compiler
//   memory fence (no TBAA/fence risk -- R7/R8's fence path stays quarantined).
//   32 blocks/CU (LDS 4864B, launch_bounds(64,8)) = 32 independent waves/CU.
// Carried from R11 (harness-verified correct): CP1=295 (conflicts halved,
//   measured 1.44e7 -> 7.2e6). Reverted from R11: dwordx4 gather (suspected
//   regression: 4B-aligned 16B memcpy + guard branch; back to 3 scalar dwords).
// Closed paths (do not revisit): operand swap (R9: A-lane-map not pinned on
//   circulant A -> wrong results); LDS-transpose epilogue (R10: -12us);
//   store coalescing is NOT the bottleneck (R10).
#define NBATCH 4
#define NV     50000
#define VPB    4           // vertices per block (1 wave x 4 vertices)
#define VST    304         // per-vertex stride = 2*VST elems
#define CP1    295         // copy-1 element offset: odd, ==7 mod 32 (bank fix)

typedef __attribute__((ext_vector_type(8))) short short8;
typedef __attribute__((ext_vector_type(4))) float floatx4;

// ---- pre-kernel: build per-lane W fragments (bf16) into d_ws ----
// layout: lane*40 + kc*8 ushorts (16B per chunk, 80B per lane, 5120B total)
__global__ void build_wfrag(const float* __restrict__ kw,
                            unsigned short* __restrict__ wbuf) {
    const int lane = threadIdx.x;      // 0..63
    const int fcol = lane & 15;
    const int quad = lane >> 4;
    #pragma unroll
    for (int kc = 0; kc < 5; ++kc) {
        unsigned short v[8];
        #pragma unroll
        for (int j = 0; j < 8; ++j) {
            int k = kc * 32 + quad * 8 + j;
            unsigned short b = 0;
            if (k < 144) {
                int dd = k / 9;
                int q  = k - dd * 9;
                int r  = q / 3;
                int c  = q - r * 3;
                __hip_bfloat16 h = __float2bfloat16(kw[((r * 16 + dd) * 3 + c) * 16 + fcol]);
                __builtin_memcpy(&b, &h, 2);
            }
            v[j] = b;
        }
        __builtin_memcpy(wbuf + lane * 40 + kc * 8, v, 16);
    }
}

__global__ __launch_bounds__(64, 8)
void input3d_mfma(const float* __restrict__ bp,     // (B,NV,3)
                  const float* __restrict__ fr,     // (B,NV,3,3)
                  const int2*  __restrict__ em,     // (B,NV,3,16) int pairs
                  const unsigned short* __restrict__ wbuf, // prebuilt W frags
                  const float* __restrict__ bias,   // (16)
                  float*       __restrict__ out)    // (B,NV,16,16)
{
    __shared__ __align__(16) unsigned short yls[VPB * 2 * VST];   // 4864 B

    const int tid  = threadIdx.x;      // 0..63 (one wave)
    const int bv0  = blockIdx.x * VPB;
    const int lane = tid;
    const int fcol = lane & 15;
    const int quad = lane >> 4;

    // ---- load prebuilt W fragments: 5 x dwordx4 ----
    union WU { unsigned short s[8]; short8 v; };
    WU wf[5];
    const unsigned short* wl = wbuf + lane * 40;
    #pragma unroll
    for (int kc = 0; kc < 5; ++kc)
        __builtin_memcpy(&wf[kc].s[0], wl + kc * 8, 16);
    const float bsf = bias[fcol];

    // ---- staging: thread = (v = tid>>4, dir = tid&15) ----
    {
        const int v   = tid >> 4;      // 0..3
        const int dir = tid & 15;
        const int bv  = bv0 + v;
        float F[9];
        __builtin_memcpy(&F[0], fr + (size_t)bv * 9, 16);
        __builtin_memcpy(&F[4], fr + (size_t)bv * 9 + 4, 16);
        F[8] = fr[(size_t)bv * 9 + 8];
        const float c0 = bp[bv * 3 + 0];
        const float c1 = bp[bv * 3 + 1];
        const float c2 = bp[bv * 3 + 2];

        unsigned short val[9];
        #pragma unroll
        for (int r = 0; r < 3; ++r) {
            int2 e  = em[bv * 48 + r * 16 + dir];
            int nb  = e.x * NV + e.y;
            float dx = bp[nb * 3 + 0] - c0;
            float dy = bp[nb * 3 + 1] - c1;
            float dz = bp[nb * 3 + 2] - c2;
            #pragma unroll
            for (int c = 0; c < 3; ++c) {
                float yv = F[c * 3 + 0] * dx + F[c * 3 + 1] * dy + F[c * 3 + 2] * dz;
                __hip_bfloat16 h = __float2bfloat16(yv);
                unsigned short us;
                __builtin_memcpy(&us, &h, 2);
                val[r * 3 + c] = us;
            }
        }

        // packed 9-element group writes (4 x b32 + 1 x u16 per group)
        unsigned short* buf = &yls[v * 2 * VST];
        unsigned int pe[4], po[4];
        #pragma unroll
        for (int i = 0; i < 4; ++i) {
            pe[i] = (unsigned int)val[2 * i]     | ((unsigned int)val[2 * i + 1] << 16);
            po[i] = (unsigned int)val[2 * i + 1] | ((unsigned int)val[2 * i + 2] << 16);
        }
        const int n0 = dir * 9;
        // even-start group: dwords at s, tail u16 at s+8
        auto storeE = [&](int s) {
            unsigned int* p = (unsigned int*)(buf + s);
            p[0] = pe[0]; p[1] = pe[1]; p[2] = pe[2]; p[3] = pe[3];
            buf[s + 8] = val[8];
        };
        // odd-start group: head u16 at s, dwords at s+1
        auto storeO = [&](int s) {
            buf[s] = val[0];
            unsigned int* p = (unsigned int*)(buf + s + 1);
            p[0] = po[0]; p[1] = po[1]; p[2] = po[2]; p[3] = po[3];
        };
        if (dir & 1) {                 // n0 odd
            storeO(n0);
            storeE(CP1 + n0);          // 295+odd = even start
            if (dir < 15) { storeO(n0 + 144); storeE(CP1 + n0 + 144); }
        } else {                       // n0 even
            storeE(n0);
            storeO(CP1 + n0);          // 295+even = odd start
            if (dir < 15) { storeE(n0 + 144); storeO(CP1 + n0 + 144); }
        }
    }
    // single-wave workgroup: s_barrier is immediate; this is kept purely as a
    // correct, compiler-visible memory fence for the LDS write->read handoff.
    __syncthreads();

    // ---- this wave: 4 vertices, 5 MFMA each (K=144 exact) ----
    floatx4 acc[4] = {{0.f,0.f,0.f,0.f},{0.f,0.f,0.f,0.f},
                      {0.f,0.f,0.f,0.f},{0.f,0.f,0.f,0.f}};
    const unsigned short* abase[4];
    #pragma unroll
    for (int i = 0; i < 4; ++i) {
        abase[i] = &yls[i * 2 * VST + ((fcol & 1) ? CP1 : 0) + 9 * fcol];
    }
    #pragma unroll
    for (int kc = 0; kc < 4; ++kc) {
        const int s = kc * 32 + quad * 8;
        #pragma unroll
        for (int i = 0; i < 4; ++i) {
            const unsigned int* pa = (const unsigned int*)(abase[i] + s);
            union { unsigned int u[4]; short8 s8; } a;
            a.u[0] = pa[0]; a.u[1] = pa[1]; a.u[2] = pa[2]; a.u[3] = pa[3];
            acc[i] = __builtin_amdgcn_mfma_f32_16x16x32_bf16(a.s8, wf[kc].v, acc[i], 0, 0, 0);
        }
    }
    {   // chunk 4: k = 128 + quad*8 + j; valid k<144 only for quads 0,1.
        const int s = 128 + quad * 8;
        #pragma unroll
        for (int i = 0; i < 4; ++i) {
            union { unsigned int u[4]; short8 s8; } a;
            if (quad < 2) {
                const unsigned int* pa = (const unsigned int*)(abase[i] + s);
                a.u[0] = pa[0]; a.u[1] = pa[1]; a.u[2] = pa[2]; a.u[3] = pa[3];
            } else {
                a.u[0] = 0; a.u[1] = 0; a.u[2] = 0; a.u[3] = 0;
            }
            acc[i] = __builtin_amdgcn_mfma_f32_16x16x32_bf16(a.s8, wf[4].v, acc[i], 0, 0, 0);
        }
    }

    // ---- epilogue: R6 scattered stores (proven fine; not the bottleneck) ----
    // C layout col=lane&15=f, row=quad*4+reg=d -> direct store.
    #pragma unroll
    for (int i = 0; i < 4; ++i) {
        int vg = bv0 + i;
        float* ob = out + (size_t)vg * 256;
        #pragma unroll
        for (int rr = 0; rr < 4; ++rr) {
            float o = acc[i][rr] + bsf;
            o = o > 0.f ? o : 0.f;
            ob[(quad * 4 + rr) * 16 + fcol] = o;
        }
    }
}

extern "C" void kernel_launch(void* const* d_in, const int* in_sizes, int n_in,
                              void* d_out, int out_size, void* d_ws, size_t ws_size,
                              hipStream_t stream) {
    const float* bp   = (const float*)d_in[0];
    const float* fr   = (const float*)d_in[1];
    const int2*  em   = (const int2*)d_in[2];
    const float* kw   = (const float*)d_in[3];
    const float* bias = (const float*)d_in[4];
    float* out = (float*)d_out;
    unsigned short* wbuf = (unsigned short*)d_ws;   // 5120 B used

    build_wfrag<<<1, 64, 0, stream>>>(kw, wbuf);

    const int total_bv = NBATCH * NV;          // 200000
    const int grid = total_bv / VPB;           // 50000 blocks (1 wave each)
    input3d_mfma<<<grid, 64, 0, stream>>>(bp, fr, em, wbuf, bias, out);
}